// Round 1
// baseline (450.574 us; speedup 1.0000x reference)
//
#include <hip/hip_runtime.h>
#include <cstdint>
#include <cstddef>

#define BN 4
#define CN 64
#define NN 4096
#define GN 32
#define TN 77
#define DN 768
#define EPSV 1e-5f
#define SCALEV 0.125f
#define LOG2E 1.4426950408889634f

typedef __bf16 bf16_t;
typedef __attribute__((ext_vector_type(8))) __bf16 bf16x8;
typedef __attribute__((ext_vector_type(4))) __bf16 bf16x4;
typedef __attribute__((ext_vector_type(4))) float f32x4;

// ---------------- K1: GroupNorm stats (per (b,g): 2 channels x 4096) ----------------
__global__ __launch_bounds__(256) void k_gnstats(const float* __restrict__ x,
                                                 float* __restrict__ mean_o,
                                                 float* __restrict__ rstd_o) {
  int bg = blockIdx.x;                       // b*32+g ; data contiguous: (b*32+g)*8192
  const float4* base = reinterpret_cast<const float4*>(x + (size_t)bg * 8192);
  float s = 0.f, sq = 0.f;
  for (int i = threadIdx.x; i < 2048; i += 256) {
    float4 v = base[i];
    s  += v.x + v.y + v.z + v.w;
    sq += v.x*v.x + v.y*v.y + v.z*v.z + v.w*v.w;
  }
  for (int off = 32; off; off >>= 1) { s += __shfl_down(s, off); sq += __shfl_down(sq, off); }
  __shared__ float ss[4], ssq[4];
  int w = threadIdx.x >> 6, l = threadIdx.x & 63;
  if (l == 0) { ss[w] = s; ssq[w] = sq; }
  __syncthreads();
  if (threadIdx.x == 0) {
    float st = ss[0] + ss[1] + ss[2] + ss[3];
    float sqt = ssq[0] + ssq[1] + ssq[2] + ssq[3];
    float mu = st / 8192.f;
    float var = sqt / 8192.f - mu * mu;
    mean_o[bg] = mu;
    rstd_o[bg] = rsqrtf(var + EPSV);
  }
}

// ---------------- K2: apply GN + QKV 1x1 conv; emit bf16 q(*0.125), k, v^T ----------------
__global__ __launch_bounds__(256) void k_gn_qkv(const float* __restrict__ x,
    const float* __restrict__ mean, const float* __restrict__ rstd,
    const float* __restrict__ gns, const float* __restrict__ gnb,
    const float* __restrict__ qkvw, const float* __restrict__ qkvb,
    bf16_t* __restrict__ qb, bf16_t* __restrict__ kb, bf16_t* __restrict__ vT) {
  __shared__ float hn[64][64];               // [c][p]
  int bx = blockIdx.x; int b = bx >> 6; int t0 = (bx & 63) << 6;
  int tid = threadIdx.x;
  {
    int c = tid >> 2, p0 = (tid & 3) << 4;
    float mu = mean[(b << 5) + (c >> 1)], rs = rstd[(b << 5) + (c >> 1)];
    float sc = gns[c] * rs, bi = gnb[c] - mu * sc;
    const float* xp = x + ((size_t)(b * 64 + c)) * NN + t0 + p0;
    #pragma unroll
    for (int j = 0; j < 16; j += 4) {
      float4 v = *reinterpret_cast<const float4*>(xp + j);
      hn[c][p0+j] = v.x*sc+bi; hn[c][p0+j+1] = v.y*sc+bi;
      hn[c][p0+j+2] = v.z*sc+bi; hn[c][p0+j+3] = v.w*sc+bi;
    }
  }
  __syncthreads();
  // q and k sections: lane -> output channel (coalesced bf16 stores)
  {
    int o0 = tid & 63, ps = tid >> 6;
    for (int sec = 0; sec < 2; ++sec) {
      int o = sec * 64 + o0;
      const float* wr = qkvw + o * 64;
      float acc[16];
      float bias = qkvb[o];
      #pragma unroll
      for (int m = 0; m < 16; m++) acc[m] = bias;
      for (int cc = 0; cc < 64; ++cc) {
        float wv = wr[cc];
        #pragma unroll
        for (int m = 0; m < 16; m++) acc[m] += hn[cc][ps + 4*m] * wv;
      }
      bf16_t* dst = (sec == 0) ? qb : kb;
      float mul = (sec == 0) ? SCALEV : 1.0f;
      #pragma unroll
      for (int m = 0; m < 16; m++) {
        int p = ps + 4*m;
        dst[((size_t)(b * NN) + t0 + p) * 64 + o0] = (bf16_t)(acc[m] * mul);
      }
    }
  }
  // v section: lane -> position (coalesced stores into v^T rows)
  {
    int p = tid & 63, ob = tid >> 6;
    for (int m = 0; m < 16; m++) {
      int o = 128 + ob + 4*m;
      const float* wr = qkvw + o * 64;
      float acc = qkvb[o];
      for (int cc = 0; cc < 64; ++cc) acc += hn[cc][p] * wr[cc];
      vT[((size_t)(b * 64) + (o - 128)) * NN + t0 + p] = (bf16_t)acc;
    }
  }
}

// ---------------- K3: flash self-attention (bf16 MFMA, swapped QK^T) ----------------
__global__ __launch_bounds__(256) void k_attn(const bf16_t* __restrict__ qb,
    const bf16_t* __restrict__ kb, const bf16_t* __restrict__ vT,
    float* __restrict__ so) {
  int bx = blockIdx.x; int b = bx >> 6; int qt = bx & 63;
  int tid = threadIdx.x; int w = tid >> 6, l = tid & 63;
  int lo = l & 15, g = l >> 4;
  int qbase = (qt << 6) + (w << 4);
  const bf16_t* qrow = qb + ((size_t)(b * NN) + qbase + lo) * 64;
  bf16x8 qf[2];
  #pragma unroll
  for (int hf = 0; hf < 2; hf++) {
    bf16x4 a  = *reinterpret_cast<const bf16x4*>(qrow + 32*hf + 4*g);
    bf16x4 c2 = *reinterpret_cast<const bf16x4*>(qrow + 32*hf + 16 + 4*g);
    #pragma unroll
    for (int i = 0; i < 4; i++) { qf[hf][i] = a[i]; qf[hf][i+4] = c2[i]; }
  }
  f32x4 oacc[4];
  #pragma unroll
  for (int nt = 0; nt < 4; nt++) oacc[nt] = (f32x4){0.f, 0.f, 0.f, 0.f};
  float m_run = -1e30f, l_run = 0.f;
  const bf16_t* kbB = kb + (size_t)b * NN * 64;
  const bf16_t* vB  = vT + (size_t)b * 64 * NN;

  for (int kt = 0; kt < 64; ++kt) {
    int k0 = kt << 6;
    float s[4][4];
    #pragma unroll
    for (int c = 0; c < 4; c++) {
      f32x4 sa = (f32x4){0.f, 0.f, 0.f, 0.f};
      const bf16_t* krow = kbB + ((size_t)(k0 + (c << 4) + lo)) * 64;
      #pragma unroll
      for (int hf = 0; hf < 2; hf++) {
        bf16x8 kf;
        bf16x4 a  = *reinterpret_cast<const bf16x4*>(krow + 32*hf + 4*g);
        bf16x4 c2 = *reinterpret_cast<const bf16x4*>(krow + 32*hf + 16 + 4*g);
        #pragma unroll
        for (int i = 0; i < 4; i++) { kf[i] = a[i]; kf[i+4] = c2[i]; }
        sa = __builtin_amdgcn_mfma_f32_16x16x32_bf16(kf, qf[hf], sa, 0, 0, 0);
      }
      #pragma unroll
      for (int r = 0; r < 4; r++) s[c][r] = sa[r];
    }
    // online softmax; stats live in "q = lane&15" layout
    float pmax = -1e30f;
    #pragma unroll
    for (int c = 0; c < 4; c++)
      #pragma unroll
      for (int r = 0; r < 4; r++) pmax = fmaxf(pmax, s[c][r]);
    pmax = fmaxf(pmax, __shfl_xor(pmax, 16));
    pmax = fmaxf(pmax, __shfl_xor(pmax, 32));
    float m_new = fmaxf(m_run, pmax);
    float corr = exp2f((m_run - m_new) * LOG2E);
    float p[4][4]; float lsum = 0.f;
    #pragma unroll
    for (int c = 0; c < 4; c++)
      #pragma unroll
      for (int r = 0; r < 4; r++) {
        float pv = exp2f((s[c][r] - m_new) * LOG2E);
        p[c][r] = pv; lsum += pv;
      }
    lsum += __shfl_xor(lsum, 16);
    lsum += __shfl_xor(lsum, 32);
    l_run = l_run * corr + lsum;
    m_run = m_new;
    float fr[4];
    #pragma unroll
    for (int r = 0; r < 4; r++) fr[r] = __shfl(corr, (g << 2) + r);
    #pragma unroll
    for (int nt = 0; nt < 4; nt++)
      #pragma unroll
      for (int r = 0; r < 4; r++) oacc[nt][r] *= fr[r];
    // P -> bf16 A-fragments (zero shuffles)
    bf16x8 pa[2];
    #pragma unroll
    for (int f_ = 0; f_ < 2; ++f_)
      #pragma unroll
      for (int i = 0; i < 8; i++) pa[f_][i] = (bf16_t)p[2*f_ + (i >> 2)][i & 3];
    // PV
    #pragma unroll
    for (int f_ = 0; f_ < 2; ++f_) {
      int kk = k0 + 32*f_ + 4*g;
      #pragma unroll
      for (int nt = 0; nt < 4; ++nt) {
        const bf16_t* vrow = vB + ((size_t)(lo + (nt << 4))) * NN;
        bf16x8 vf;
        bf16x4 a  = *reinterpret_cast<const bf16x4*>(vrow + kk);
        bf16x4 c2 = *reinterpret_cast<const bf16x4*>(vrow + kk + 16);
        #pragma unroll
        for (int i = 0; i < 4; i++) { vf[i] = a[i]; vf[i+4] = c2[i]; }
        oacc[nt] = __builtin_amdgcn_mfma_f32_16x16x32_bf16(pa[f_], vf, oacc[nt], 0, 0, 0);
      }
    }
  }
  float linv[4];
  #pragma unroll
  for (int r = 0; r < 4; r++) linv[r] = 1.0f / __shfl(l_run, (g << 2) + r);
  #pragma unroll
  for (int nt = 0; nt < 4; nt++)
    #pragma unroll
    for (int r = 0; r < 4; r++)
      so[((size_t)(b * NN) + qbase + (g << 2) + r) * 64 + lo + (nt << 4)] =
          oacc[nt][r] * linv[r];
}

// ---------------- K4: proj + residual -> h2 ; LayerNorm ; tq (*0.125) ----------------
__global__ __launch_bounds__(256) void k_proj_ln_tq(const float* __restrict__ x,
    const float* __restrict__ so, const float* __restrict__ projw, const float* __restrict__ projb,
    const float* __restrict__ lns, const float* __restrict__ lnb,
    const float* __restrict__ wq, const float* __restrict__ bq,
    float* __restrict__ h2, float* __restrict__ tq) {
  __shared__ float sob[64][65];   // self_out tile [p][c], later reused as tf [p][c]
  __shared__ float h2l[64][65];   // h2 tile [o][p]
  __shared__ float mu_s[64], rs_s[64];
  int bx = blockIdx.x; int b = bx >> 6; int t0 = (bx & 63) << 6;
  int tid = threadIdx.x;
  {
    int p = tid >> 2, c0 = (tid & 3) << 4;
    const float* src = so + ((size_t)(b * NN) + t0 + p) * 64 + c0;
    #pragma unroll
    for (int j = 0; j < 16; j += 4) {
      float4 v = *reinterpret_cast<const float4*>(src + j);
      sob[p][c0+j] = v.x; sob[p][c0+j+1] = v.y; sob[p][c0+j+2] = v.z; sob[p][c0+j+3] = v.w;
    }
  }
  __syncthreads();
  {
    int p = tid & 63, ob = tid >> 6;
    float acc[16];
    #pragma unroll
    for (int m = 0; m < 16; m++) {
      int o = ob + 4*m;
      acc[m] = projb[o] + x[((size_t)(b * 64) + o) * NN + t0 + p];
    }
    for (int cc = 0; cc < 64; ++cc) {
      float sv = sob[p][cc];
      #pragma unroll
      for (int m = 0; m < 16; m++) acc[m] += sv * projw[(ob + 4*m) * 64 + cc];
    }
    #pragma unroll
    for (int m = 0; m < 16; m++) {
      int o = ob + 4*m;
      h2[((size_t)(b * 64) + o) * NN + t0 + p] = acc[m];
      h2l[o][p] = acc[m];
    }
  }
  __syncthreads();
  if (tid < 64) {
    int p = tid;
    float s = 0.f, sq = 0.f;
    for (int o = 0; o < 64; o++) { float v = h2l[o][p]; s += v; sq += v*v; }
    float mu = s * (1.f/64.f);
    float var = sq * (1.f/64.f) - mu*mu;
    mu_s[p] = mu; rs_s[p] = rsqrtf(var + EPSV);
  }
  __syncthreads();
  {
    int p = tid & 63, cb = tid >> 6;
    float mu = mu_s[p], rs = rs_s[p];
    #pragma unroll
    for (int m = 0; m < 16; m++) {
      int c = cb + 4*m;
      sob[p][c] = (h2l[c][p] - mu) * rs * lns[c] + lnb[c];
    }
  }
  __syncthreads();
  {
    int o = tid & 63, pb = tid >> 6;
    float acc[16];
    #pragma unroll
    for (int m = 0; m < 16; m++) acc[m] = bq[o];
    for (int cc = 0; cc < 64; ++cc) {
      float wv = wq[cc * 64 + o];
      #pragma unroll
      for (int m = 0; m < 16; m++) acc[m] += sob[pb + 4*m][cc] * wv;
    }
    #pragma unroll
    for (int m = 0; m < 16; m++) {
      int p = pb + 4*m;
      tq[((size_t)(b * NN) + t0 + p) * 64 + o] = acc[m] * SCALEV;
    }
  }
}

// ---------------- K5: tk, tv = context @ wk/wv + b ----------------
__global__ __launch_bounds__(128) void k_tkv(const float* __restrict__ ctx,
    const float* __restrict__ wk, const float* __restrict__ bk,
    const float* __restrict__ wv, const float* __restrict__ bv,
    float* __restrict__ tk, float* __restrict__ tv) {
  __shared__ float cr[768];
  int bt = blockIdx.x;             // b*77 + t
  int tid = threadIdx.x;
  const float* src = ctx + (size_t)bt * 768;
  for (int i = tid; i < 768; i += 128) cr[i] = src[i];
  __syncthreads();
  int o = tid & 63;
  const float* w  = (tid < 64) ? wk : wv;
  const float* bb = (tid < 64) ? bk : bv;
  float acc = bb[o];
  for (int d = 0; d < 768; d++) acc += cr[d] * w[d * 64 + o];
  float* dst = (tid < 64) ? tk : tv;
  dst[(size_t)bt * 64 + o] = acc;
}

// ---------------- K6: cross-attn + scramble + final linear + residual ----------------
__global__ __launch_bounds__(256) void k_cross(const float* __restrict__ tq,
    const float* __restrict__ tkp, const float* __restrict__ tvp,
    const float* __restrict__ h2, const float* __restrict__ wo, const float* __restrict__ bo,
    float* __restrict__ out) {
  __shared__ float tqt[64][65];
  __shared__ float sP[64][80];
  __shared__ float tt[64][65];
  __shared__ float linv_s[64];
  int bx = blockIdx.x; int b = bx >> 6; int c = bx & 63;
  int tid = threadIdx.x;
  {
    int r = tid >> 2, o0 = (tid & 3) << 4;
    const float* src = tq + ((size_t)(b * NN) + (c << 6) + r) * 64 + o0;
    #pragma unroll
    for (int j = 0; j < 16; j += 4) {
      float4 v = *reinterpret_cast<const float4*>(src + j);
      tqt[r][o0+j] = v.x; tqt[r][o0+j+1] = v.y; tqt[r][o0+j+2] = v.z; tqt[r][o0+j+3] = v.w;
    }
  }
  __syncthreads();
  {
    int r = tid >> 2, q = tid & 3;
    const float* tkb = tkp + (size_t)b * TN * 64;
    for (int tok = q; tok < TN; tok += 4) {
      const float* krow = tkb + tok * 64;
      float acc = 0.f;
      for (int o = 0; o < 64; o++) acc += tqt[r][o] * krow[o];
      sP[r][tok] = acc;
    }
    float mx = -1e30f;
    for (int tok = q; tok < TN; tok += 4) mx = fmaxf(mx, sP[r][tok]);
    mx = fmaxf(mx, __shfl_xor(mx, 1));
    mx = fmaxf(mx, __shfl_xor(mx, 2));
    float ls = 0.f;
    for (int tok = q; tok < TN; tok += 4) {
      float pv = exp2f((sP[r][tok] - mx) * LOG2E);
      sP[r][tok] = pv; ls += pv;
    }
    ls += __shfl_xor(ls, 1);
    ls += __shfl_xor(ls, 2);
    if (q == 0) linv_s[r] = 1.0f / ls;
  }
  __syncthreads();
  {
    int o = tid & 63, rb = tid >> 6;
    const float* tvb = tvp + (size_t)b * TN * 64;
    float acc[16];
    #pragma unroll
    for (int m = 0; m < 16; m++) acc[m] = 0.f;
    for (int tok = 0; tok < TN; tok++) {
      float vv = tvb[tok * 64 + o];
      #pragma unroll
      for (int m = 0; m < 16; m++) acc[m] += sP[rb + 4*m][tok] * vv;
    }
    #pragma unroll
    for (int m = 0; m < 16; m++) {
      int r = rb + 4*m;
      tt[r][o] = acc[m] * linv_s[r];
    }
  }
  __syncthreads();
  {
    int ww = tid & 63, hb = tid >> 6;
    const float* h2r = h2 + ((size_t)(b * 64) + c) * NN;
    float bov = bo[ww];
    float acc[16];
    #pragma unroll
    for (int m = 0; m < 16; m++) acc[m] = h2r[((hb + 4*m) << 6) + ww] + bov;
    for (int k = 0; k < 64; k++) {
      float wv = wo[(k << 6) + ww];
      #pragma unroll
      for (int m = 0; m < 16; m++) acc[m] += tt[k][hb + 4*m] * wv;
    }
    #pragma unroll
    for (int m = 0; m < 16; m++)
      out[((size_t)(b * 64) + c) * NN + ((hb + 4*m) << 6) + ww] = acc[m];
  }
}

extern "C" void kernel_launch(void* const* d_in, const int* in_sizes, int n_in,
                              void* d_out, int out_size, void* d_ws, size_t ws_size,
                              hipStream_t stream) {
  const float* x     = (const float*)d_in[0];
  const float* ctx   = (const float*)d_in[1];
  const float* gns   = (const float*)d_in[2];
  const float* gnb   = (const float*)d_in[3];
  const float* qkvw  = (const float*)d_in[4];
  const float* qkvb  = (const float*)d_in[5];
  const float* projw = (const float*)d_in[6];
  const float* projb = (const float*)d_in[7];
  const float* lns   = (const float*)d_in[8];
  const float* lnb   = (const float*)d_in[9];
  const float* wq    = (const float*)d_in[10];
  const float* bq    = (const float*)d_in[11];
  const float* wk    = (const float*)d_in[12];
  const float* bk    = (const float*)d_in[13];
  const float* wv    = (const float*)d_in[14];
  const float* bv    = (const float*)d_in[15];
  const float* wo    = (const float*)d_in[16];
  const float* bo    = (const float*)d_in[17];
  float* out = (float*)d_out;

  char* ws = (char*)d_ws;
  float* gmean = (float*)ws;                       // 128
  float* grstd = gmean + 128;                      // 128
  bf16_t* qb   = (bf16_t*)(ws + 1024);
  bf16_t* kbuf = qb + (size_t)BN * NN * 64;
  bf16_t* vT   = kbuf + (size_t)BN * NN * 64;
  float* so  = (float*)(ws + 1024 + 3 * (size_t)BN * NN * 64 * 2);
  float* h2  = so + (size_t)BN * NN * 64;
  float* tqb = h2 + (size_t)BN * NN * 64;
  float* tkb = tqb + (size_t)BN * NN * 64;
  float* tvb = tkb + (size_t)BN * TN * 64;

  k_gnstats<<<dim3(128), dim3(256), 0, stream>>>(x, gmean, grstd);
  k_gn_qkv<<<dim3(256), dim3(256), 0, stream>>>(x, gmean, grstd, gns, gnb, qkvw, qkvb,
                                                qb, kbuf, vT);
  k_attn<<<dim3(256), dim3(256), 0, stream>>>(qb, kbuf, vT, so);
  k_proj_ln_tq<<<dim3(256), dim3(256), 0, stream>>>(x, so, projw, projb, lns, lnb, wq, bq,
                                                    h2, tqb);
  k_tkv<<<dim3(BN * TN), dim3(128), 0, stream>>>(ctx, wk, bk, wv, bv, tkb, tvb);
  k_cross<<<dim3(256), dim3(256), 0, stream>>>(tqb, tkb, tvb, h2, wo, bo, out);
}

// Round 2
// 263.910 us; speedup vs baseline: 1.7073x; 1.7073x over previous
//
#include <hip/hip_runtime.h>
#include <cstdint>
#include <cstddef>

#define BN 4
#define CN 64
#define NN 4096
#define GN 32
#define TN 77
#define DN 768
#define EPSV 1e-5f
#define SCALEV 0.125f
#define LOG2E 1.4426950408889634f
#define NSPLIT 4

typedef __bf16 bf16_t;
typedef __attribute__((ext_vector_type(8))) __bf16 bf16x8;
typedef __attribute__((ext_vector_type(4))) __bf16 bf16x4;
typedef __attribute__((ext_vector_type(4))) float f32x4;

#define EXP2(x) __builtin_amdgcn_exp2f(x)

// ---------------- K1: GroupNorm stats (per (b,g): 2 channels x 4096) ----------------
__global__ __launch_bounds__(256) void k_gnstats(const float* __restrict__ x,
                                                 float* __restrict__ mean_o,
                                                 float* __restrict__ rstd_o) {
  int bg = blockIdx.x;
  const float4* base = reinterpret_cast<const float4*>(x + (size_t)bg * 8192);
  float s = 0.f, sq = 0.f;
  for (int i = threadIdx.x; i < 2048; i += 256) {
    float4 v = base[i];
    s  += v.x + v.y + v.z + v.w;
    sq += v.x*v.x + v.y*v.y + v.z*v.z + v.w*v.w;
  }
  for (int off = 32; off; off >>= 1) { s += __shfl_down(s, off); sq += __shfl_down(sq, off); }
  __shared__ float ss[4], ssq[4];
  int w = threadIdx.x >> 6, l = threadIdx.x & 63;
  if (l == 0) { ss[w] = s; ssq[w] = sq; }
  __syncthreads();
  if (threadIdx.x == 0) {
    float st = ss[0] + ss[1] + ss[2] + ss[3];
    float sqt = ssq[0] + ssq[1] + ssq[2] + ssq[3];
    float mu = st / 8192.f;
    float var = sqt / 8192.f - mu * mu;
    mean_o[bg] = mu;
    rstd_o[bg] = rsqrtf(var + EPSV);
  }
}

// fragment-order channel permutation for Q/K rows (slot position of channel o)
__device__ __forceinline__ int fragpos(int o) {
  return ((o >> 2) & 3) * 16 + ((o >> 4) & 1) * 4 + ((o >> 5) & 1) * 8 + (o & 3);
}

// ---------------- K2: apply GN + QKV 1x1 conv; emit bf16 q(*0.125), k, v^T ----------------
// q,k stored per-row in fragment order; v^T stored [c][key] with 32-key blocks permuted.
__global__ __launch_bounds__(256) void k_gn_qkv(const float* __restrict__ x,
    const float* __restrict__ mean, const float* __restrict__ rstd,
    const float* __restrict__ gns, const float* __restrict__ gnb,
    const float* __restrict__ qkvw, const float* __restrict__ qkvb,
    bf16_t* __restrict__ qb, bf16_t* __restrict__ kb, bf16_t* __restrict__ vT) {
  __shared__ float hn[64][64];               // [c][p]
  int bx = blockIdx.x; int b = bx >> 6; int t0 = (bx & 63) << 6;
  int tid = threadIdx.x;
  {
    int c = tid >> 2, p0 = (tid & 3) << 4;
    float mu = mean[(b << 5) + (c >> 1)], rs = rstd[(b << 5) + (c >> 1)];
    float sc = gns[c] * rs, bi = gnb[c] - mu * sc;
    const float* xp = x + ((size_t)(b * 64 + c)) * NN + t0 + p0;
    #pragma unroll
    for (int j = 0; j < 16; j += 4) {
      float4 v = *reinterpret_cast<const float4*>(xp + j);
      hn[c][p0+j] = v.x*sc+bi; hn[c][p0+j+1] = v.y*sc+bi;
      hn[c][p0+j+2] = v.z*sc+bi; hn[c][p0+j+3] = v.w*sc+bi;
    }
  }
  __syncthreads();
  // q and k sections
  {
    int o0 = tid & 63, ps = tid >> 6;
    int pq = fragpos(o0);
    for (int sec = 0; sec < 2; ++sec) {
      int o = sec * 64 + o0;
      const float* wr = qkvw + o * 64;
      float acc[16];
      float bias = qkvb[o];
      #pragma unroll
      for (int m = 0; m < 16; m++) acc[m] = bias;
      for (int cc = 0; cc < 64; ++cc) {
        float wv = wr[cc];
        #pragma unroll
        for (int m = 0; m < 16; m++) acc[m] += hn[cc][ps + 4*m] * wv;
      }
      bf16_t* dst = (sec == 0) ? qb : kb;
      float mul = (sec == 0) ? SCALEV : 1.0f;
      #pragma unroll
      for (int m = 0; m < 16; m++) {
        int p = ps + 4*m;
        dst[((size_t)(b * NN) + t0 + p) * 64 + pq] = (bf16_t)(acc[m] * mul);
      }
    }
  }
  // v section
  {
    int p = tid & 63, ob = tid >> 6;
    int pbase = (p & 32) + ((p >> 2) & 3) * 8 + ((p >> 4) & 1) * 4 + (p & 3);
    for (int m = 0; m < 16; m++) {
      int o = 128 + ob + 4*m;
      const float* wr = qkvw + o * 64;
      float acc = qkvb[o];
      for (int cc = 0; cc < 64; ++cc) acc += hn[cc][p] * wr[cc];
      vT[((size_t)(b * 64) + (o - 128)) * NN + t0 + pbase] = (bf16_t)acc;
    }
  }
}

// ---------------- K3: flash self-attention, KV-split x4 ----------------
__global__ __launch_bounds__(256, 4) void k_attn(const bf16_t* __restrict__ qb,
    const bf16_t* __restrict__ kb, const bf16_t* __restrict__ vT,
    float* __restrict__ opart, float* __restrict__ mpart, float* __restrict__ lpart) {
  int bx = blockIdx.x;
  int b = (bx >> 1) & 3;                       // keep each batch on one XCD pair
  int id = ((bx >> 3) << 1) | (bx & 1);        // 0..255
  int qt = id & 63;
  int split = id >> 6;
  int tid = threadIdx.x; int w = tid >> 6, l = tid & 63;
  int lo = l & 15, g = l >> 4;
  int qbase = (qt << 6) + (w << 4);
  const bf16_t* qrow = qb + (((size_t)(b * NN) + qbase + lo) << 6) + g * 16;
  bf16x8 qf0 = *reinterpret_cast<const bf16x8*>(qrow);
  bf16x8 qf1 = *reinterpret_cast<const bf16x8*>(qrow + 8);
  f32x4 oacc[4];
  #pragma unroll
  for (int nt = 0; nt < 4; nt++) oacc[nt] = (f32x4){0.f, 0.f, 0.f, 0.f};
  float m_run = -1e30f, l_run = 0.f;
  const bf16_t* kbB = kb + ((size_t)b * NN << 6);
  const bf16_t* vB  = vT + ((size_t)b * 64) * NN;
  int k0 = split << 10;

  #pragma unroll 2
  for (int t = 0; t < 16; ++t, k0 += 64) {
    // QK^T
    f32x4 sa[4];
    #pragma unroll
    for (int c = 0; c < 4; c++) {
      const bf16_t* krow = kbB + (((size_t)(k0 + (c << 4) + lo)) << 6) + g * 16;
      bf16x8 kf0 = *reinterpret_cast<const bf16x8*>(krow);
      bf16x8 kf1 = *reinterpret_cast<const bf16x8*>(krow + 8);
      sa[c] = __builtin_amdgcn_mfma_f32_16x16x32_bf16(kf0, qf0,
                  (f32x4){0.f, 0.f, 0.f, 0.f}, 0, 0, 0);
      sa[c] = __builtin_amdgcn_mfma_f32_16x16x32_bf16(kf1, qf1, sa[c], 0, 0, 0);
    }
    // issue V(f=0) loads early; softmax VALU hides their latency
    bf16x8 vf0[4];
    #pragma unroll
    for (int nt = 0; nt < 4; nt++)
      vf0[nt] = *reinterpret_cast<const bf16x8*>(vB + ((size_t)(lo + (nt << 4))) * NN + k0 + g * 8);

    // online softmax (q = lane&15)
    float pmax = -1e30f;
    #pragma unroll
    for (int c = 0; c < 4; c++)
      #pragma unroll
      for (int r = 0; r < 4; r++) pmax = fmaxf(pmax, sa[c][r]);
    pmax = fmaxf(pmax, __shfl_xor(pmax, 16));
    pmax = fmaxf(pmax, __shfl_xor(pmax, 32));
    float m_new = fmaxf(m_run, pmax);
    float corr = EXP2((m_run - m_new) * LOG2E);
    float p[4][4]; float lsum = 0.f;
    #pragma unroll
    for (int c = 0; c < 4; c++)
      #pragma unroll
      for (int r = 0; r < 4; r++) {
        float pv = EXP2((sa[c][r] - m_new) * LOG2E);
        p[c][r] = pv; lsum += pv;
      }
    lsum += __shfl_xor(lsum, 16);
    lsum += __shfl_xor(lsum, 32);
    l_run = l_run * corr + lsum;
    m_run = m_new;
    float fr[4];
    #pragma unroll
    for (int r = 0; r < 4; r++) fr[r] = __shfl(corr, (g << 2) + r);
    #pragma unroll
    for (int nt = 0; nt < 4; nt++)
      #pragma unroll
      for (int r = 0; r < 4; r++) oacc[nt][r] *= fr[r];
    // P -> bf16 A fragments
    bf16x8 pa0, pa1;
    #pragma unroll
    for (int i = 0; i < 8; i++) { pa0[i] = (bf16_t)p[i >> 2][i & 3]; pa1[i] = (bf16_t)p[2 + (i >> 2)][i & 3]; }
    // issue V(f=1) loads, then PV(f=0) hides them
    bf16x8 vf1[4];
    #pragma unroll
    for (int nt = 0; nt < 4; nt++)
      vf1[nt] = *reinterpret_cast<const bf16x8*>(vB + ((size_t)(lo + (nt << 4))) * NN + k0 + 32 + g * 8);
    #pragma unroll
    for (int nt = 0; nt < 4; ++nt)
      oacc[nt] = __builtin_amdgcn_mfma_f32_16x16x32_bf16(pa0, vf0[nt], oacc[nt], 0, 0, 0);
    #pragma unroll
    for (int nt = 0; nt < 4; ++nt)
      oacc[nt] = __builtin_amdgcn_mfma_f32_16x16x32_bf16(pa1, vf1[nt], oacc[nt], 0, 0, 0);
  }

  size_t ob = ((size_t)(split * BN + b)) * NN + qbase;
  #pragma unroll
  for (int nt = 0; nt < 4; nt++)
    #pragma unroll
    for (int r = 0; r < 4; r++)
      opart[((ob + (g << 2) + r) << 6) + lo + (nt << 4)] = oacc[nt][r];
  if (l < 16) { mpart[ob + l] = m_run; lpart[ob + l] = l_run; }
}

// ---------------- K4: combine splits + proj + residual ; LayerNorm ; tq ----------------
__global__ __launch_bounds__(256) void k_proj_ln_tq(const float* __restrict__ x,
    const float* __restrict__ opart, const float* __restrict__ mpart, const float* __restrict__ lpart,
    const float* __restrict__ projw, const float* __restrict__ projb,
    const float* __restrict__ lns, const float* __restrict__ lnb,
    const float* __restrict__ wq, const float* __restrict__ bq,
    float* __restrict__ h2, float* __restrict__ tq) {
  __shared__ float sob[64][65];
  __shared__ float h2l[64][65];
  __shared__ float mu_s[64], rs_s[64];
  int bx = blockIdx.x; int b = bx >> 6; int t0 = (bx & 63) << 6;
  int tid = threadIdx.x;
  {
    int p = tid >> 2, c0 = (tid & 3) << 4;
    int q = t0 + p;
    float ms[NSPLIT], ws[NSPLIT];
    float mstar = -1e30f;
    #pragma unroll
    for (int s = 0; s < NSPLIT; s++) {
      ms[s] = mpart[((size_t)(s * BN + b)) * NN + q];
      mstar = fmaxf(mstar, ms[s]);
    }
    float denom = 0.f;
    #pragma unroll
    for (int s = 0; s < NSPLIT; s++) {
      float wv = EXP2((ms[s] - mstar) * LOG2E);
      ws[s] = wv;
      denom += wv * lpart[((size_t)(s * BN + b)) * NN + q];
    }
    float inv = 1.0f / denom;
    float acc[16];
    #pragma unroll
    for (int j = 0; j < 16; j++) acc[j] = 0.f;
    #pragma unroll
    for (int s = 0; s < NSPLIT; s++) {
      const float* op = opart + ((((size_t)(s * BN + b)) * NN + q) << 6) + c0;
      float wv = ws[s];
      #pragma unroll
      for (int j = 0; j < 16; j += 4) {
        float4 v = *reinterpret_cast<const float4*>(op + j);
        acc[j] += wv*v.x; acc[j+1] += wv*v.y; acc[j+2] += wv*v.z; acc[j+3] += wv*v.w;
      }
    }
    #pragma unroll
    for (int j = 0; j < 16; j++) sob[p][c0 + j] = acc[j] * inv;
  }
  __syncthreads();
  {
    int p = tid & 63, ob = tid >> 6;
    float acc[16];
    #pragma unroll
    for (int m = 0; m < 16; m++) {
      int o = ob + 4*m;
      acc[m] = projb[o] + x[((size_t)(b * 64) + o) * NN + t0 + p];
    }
    for (int cc = 0; cc < 64; ++cc) {
      float sv = sob[p][cc];
      #pragma unroll
      for (int m = 0; m < 16; m++) acc[m] += sv * projw[(ob + 4*m) * 64 + cc];
    }
    #pragma unroll
    for (int m = 0; m < 16; m++) {
      int o = ob + 4*m;
      h2[((size_t)(b * 64) + o) * NN + t0 + p] = acc[m];
      h2l[o][p] = acc[m];
    }
  }
  __syncthreads();
  if (tid < 64) {
    int p = tid;
    float s = 0.f, sq = 0.f;
    for (int o = 0; o < 64; o++) { float v = h2l[o][p]; s += v; sq += v*v; }
    float mu = s * (1.f/64.f);
    float var = sq * (1.f/64.f) - mu*mu;
    mu_s[p] = mu; rs_s[p] = rsqrtf(var + EPSV);
  }
  __syncthreads();
  {
    int p = tid & 63, cb = tid >> 6;
    float mu = mu_s[p], rs = rs_s[p];
    #pragma unroll
    for (int m = 0; m < 16; m++) {
      int c = cb + 4*m;
      sob[p][c] = (h2l[c][p] - mu) * rs * lns[c] + lnb[c];
    }
  }
  __syncthreads();
  {
    int o = tid & 63, pb = tid >> 6;
    float acc[16];
    #pragma unroll
    for (int m = 0; m < 16; m++) acc[m] = bq[o];
    for (int cc = 0; cc < 64; ++cc) {
      float wv = wq[cc * 64 + o];
      #pragma unroll
      for (int m = 0; m < 16; m++) acc[m] += sob[pb + 4*m][cc] * wv;
    }
    #pragma unroll
    for (int m = 0; m < 16; m++) {
      int p = pb + 4*m;
      tq[((size_t)(b * NN) + t0 + p) * 64 + o] = acc[m] * SCALEV;
    }
  }
}

// ---------------- K5: tk, tv = context @ wk/wv + b ----------------
__global__ __launch_bounds__(128) void k_tkv(const float* __restrict__ ctx,
    const float* __restrict__ wk, const float* __restrict__ bk,
    const float* __restrict__ wv, const float* __restrict__ bv,
    float* __restrict__ tk, float* __restrict__ tv) {
  __shared__ float cr[768];
  int bt = blockIdx.x;
  int tid = threadIdx.x;
  const float* src = ctx + (size_t)bt * 768;
  for (int i = tid; i < 768; i += 128) cr[i] = src[i];
  __syncthreads();
  int o = tid & 63;
  const float* w  = (tid < 64) ? wk : wv;
  const float* bb = (tid < 64) ? bk : bv;
  float acc = bb[o];
  for (int d = 0; d < 768; d++) acc += cr[d] * w[d * 64 + o];
  float* dst = (tid < 64) ? tk : tv;
  dst[(size_t)bt * 64 + o] = acc;
}

// ---------------- K6: cross-attn + scramble + final linear + residual ----------------
__global__ __launch_bounds__(256) void k_cross(const float* __restrict__ tq,
    const float* __restrict__ tkp, const float* __restrict__ tvp,
    const float* __restrict__ h2, const float* __restrict__ wo, const float* __restrict__ bo,
    float* __restrict__ out) {
  __shared__ float tqt[64][65];
  __shared__ float sP[64][80];
  __shared__ float tt[64][65];
  __shared__ float linv_s[64];
  int bx = blockIdx.x; int b = bx >> 6; int c = bx & 63;
  int tid = threadIdx.x;
  {
    int r = tid >> 2, o0 = (tid & 3) << 4;
    const float* src = tq + ((size_t)(b * NN) + (c << 6) + r) * 64 + o0;
    #pragma unroll
    for (int j = 0; j < 16; j += 4) {
      float4 v = *reinterpret_cast<const float4*>(src + j);
      tqt[r][o0+j] = v.x; tqt[r][o0+j+1] = v.y; tqt[r][o0+j+2] = v.z; tqt[r][o0+j+3] = v.w;
    }
  }
  __syncthreads();
  {
    int r = tid >> 2, q = tid & 3;
    const float* tkb = tkp + (size_t)b * TN * 64;
    for (int tok = q; tok < TN; tok += 4) {
      const float* krow = tkb + tok * 64;
      float acc = 0.f;
      for (int o = 0; o < 64; o++) acc += tqt[r][o] * krow[o];
      sP[r][tok] = acc;
    }
    float mx = -1e30f;
    for (int tok = q; tok < TN; tok += 4) mx = fmaxf(mx, sP[r][tok]);
    mx = fmaxf(mx, __shfl_xor(mx, 1));
    mx = fmaxf(mx, __shfl_xor(mx, 2));
    float ls = 0.f;
    for (int tok = q; tok < TN; tok += 4) {
      float pv = EXP2((sP[r][tok] - mx) * LOG2E);
      sP[r][tok] = pv; ls += pv;
    }
    ls += __shfl_xor(ls, 1);
    ls += __shfl_xor(ls, 2);
    if (q == 0) linv_s[r] = 1.0f / ls;
  }
  __syncthreads();
  {
    int o = tid & 63, rb = tid >> 6;
    const float* tvb = tvp + (size_t)b * TN * 64;
    float acc[16];
    #pragma unroll
    for (int m = 0; m < 16; m++) acc[m] = 0.f;
    for (int tok = 0; tok < TN; tok++) {
      float vv = tvb[tok * 64 + o];
      #pragma unroll
      for (int m = 0; m < 16; m++) acc[m] += sP[rb + 4*m][tok] * vv;
    }
    #pragma unroll
    for (int m = 0; m < 16; m++) {
      int r = rb + 4*m;
      tt[r][o] = acc[m] * linv_s[r];
    }
  }
  __syncthreads();
  {
    int ww = tid & 63, hb = tid >> 6;
    const float* h2r = h2 + ((size_t)(b * 64) + c) * NN;
    float bov = bo[ww];
    float acc[16];
    #pragma unroll
    for (int m = 0; m < 16; m++) acc[m] = h2r[((hb + 4*m) << 6) + ww] + bov;
    for (int k = 0; k < 64; k++) {
      float wv = wo[(k << 6) + ww];
      #pragma unroll
      for (int m = 0; m < 16; m++) acc[m] += tt[k][hb + 4*m] * wv;
    }
    #pragma unroll
    for (int m = 0; m < 16; m++)
      out[((size_t)(b * 64) + c) * NN + ((hb + 4*m) << 6) + ww] = acc[m];
  }
}

extern "C" void kernel_launch(void* const* d_in, const int* in_sizes, int n_in,
                              void* d_out, int out_size, void* d_ws, size_t ws_size,
                              hipStream_t stream) {
  const float* x     = (const float*)d_in[0];
  const float* ctx   = (const float*)d_in[1];
  const float* gns   = (const float*)d_in[2];
  const float* gnb   = (const float*)d_in[3];
  const float* qkvw  = (const float*)d_in[4];
  const float* qkvb  = (const float*)d_in[5];
  const float* projw = (const float*)d_in[6];
  const float* projb = (const float*)d_in[7];
  const float* lns   = (const float*)d_in[8];
  const float* lnb   = (const float*)d_in[9];
  const float* wq    = (const float*)d_in[10];
  const float* bq    = (const float*)d_in[11];
  const float* wk    = (const float*)d_in[12];
  const float* bk    = (const float*)d_in[13];
  const float* wv    = (const float*)d_in[14];
  const float* bv    = (const float*)d_in[15];
  const float* wo    = (const float*)d_in[16];
  const float* bo    = (const float*)d_in[17];
  float* out = (float*)d_out;

  char* ws = (char*)d_ws;
  float* gmean = (float*)ws;                       // 128
  float* grstd = gmean + 128;                      // 128
  bf16_t* qb   = (bf16_t*)(ws + 1024);
  bf16_t* kbuf = qb + (size_t)BN * NN * 64;
  bf16_t* vT   = kbuf + (size_t)BN * NN * 64;
  float* opart = (float*)(ws + 1024 + 3 * (size_t)BN * NN * 64 * 2);  // 16 MB
  float* mpart = opart + (size_t)NSPLIT * BN * NN * 64;
  float* lpart = mpart + (size_t)NSPLIT * BN * NN;
  float* h2  = lpart + (size_t)NSPLIT * BN * NN;
  float* tqb = h2 + (size_t)BN * NN * 64;
  float* tkb = tqb + (size_t)BN * NN * 64;
  float* tvb = tkb + (size_t)BN * TN * 64;

  k_gnstats<<<dim3(128), dim3(256), 0, stream>>>(x, gmean, grstd);
  k_gn_qkv<<<dim3(256), dim3(256), 0, stream>>>(x, gmean, grstd, gns, gnb, qkvw, qkvb,
                                                qb, kbuf, vT);
  k_attn<<<dim3(256 * NSPLIT), dim3(256), 0, stream>>>(qb, kbuf, vT, opart, mpart, lpart);
  k_proj_ln_tq<<<dim3(256), dim3(256), 0, stream>>>(x, opart, mpart, lpart, projw, projb,
                                                    lns, lnb, wq, bq, h2, tqb);
  k_tkv<<<dim3(BN * TN), dim3(128), 0, stream>>>(ctx, wk, bk, wv, bv, tkb, tvb);
  k_cross<<<dim3(256), dim3(256), 0, stream>>>(tqb, tkb, tvb, h2, wo, bo, out);
}

// Round 3
// 221.136 us; speedup vs baseline: 2.0375x; 1.1934x over previous
//
#include <hip/hip_runtime.h>
#include <cstdint>
#include <cstddef>

#define BN 4
#define CN 64
#define NN 4096
#define GN 32
#define TN 77
#define DN 768
#define EPSV 1e-5f
#define SCALEV 0.125f
#define LOG2E 1.4426950408889634f
#define NSPLIT 8

typedef __bf16 bf16_t;
typedef __attribute__((ext_vector_type(8))) __bf16 bf16x8;
typedef __attribute__((ext_vector_type(4))) __bf16 bf16x4;
typedef __attribute__((ext_vector_type(4))) float f32x4;

#define EXP2(x) __builtin_amdgcn_exp2f(x)

// ---------------- K1: GroupNorm stats (per (b,g): 2 channels x 4096) ----------------
__global__ __launch_bounds__(256) void k_gnstats(const float* __restrict__ x,
                                                 float* __restrict__ mean_o,
                                                 float* __restrict__ rstd_o) {
  int bg = blockIdx.x;
  const float4* base = reinterpret_cast<const float4*>(x + (size_t)bg * 8192);
  float s = 0.f, sq = 0.f;
  for (int i = threadIdx.x; i < 2048; i += 256) {
    float4 v = base[i];
    s  += v.x + v.y + v.z + v.w;
    sq += v.x*v.x + v.y*v.y + v.z*v.z + v.w*v.w;
  }
  for (int off = 32; off; off >>= 1) { s += __shfl_down(s, off); sq += __shfl_down(sq, off); }
  __shared__ float ss[4], ssq[4];
  int w = threadIdx.x >> 6, l = threadIdx.x & 63;
  if (l == 0) { ss[w] = s; ssq[w] = sq; }
  __syncthreads();
  if (threadIdx.x == 0) {
    float st = ss[0] + ss[1] + ss[2] + ss[3];
    float sqt = ssq[0] + ssq[1] + ssq[2] + ssq[3];
    float mu = st / 8192.f;
    float var = sqt / 8192.f - mu * mu;
    mean_o[bg] = mu;
    rstd_o[bg] = rsqrtf(var + EPSV);
  }
}

// fragment-order channel permutation for Q/K rows (slot position of channel o)
__device__ __forceinline__ int fragpos(int o) {
  return ((o >> 2) & 3) * 16 + ((o >> 4) & 1) * 4 + ((o >> 5) & 1) * 8 + (o & 3);
}
// within-64-key permutation for V rows
__device__ __forceinline__ int vperm(int p) {
  return (p & 32) + ((p >> 2) & 3) * 8 + ((p >> 4) & 1) * 4 + (p & 3);
}

// ---------------- K2: GN apply + QKV 1x1; 32-position tiles (512 blocks) ----------------
__global__ __launch_bounds__(256) void k_gn_qkv(const float* __restrict__ x,
    const float* __restrict__ mean, const float* __restrict__ rstd,
    const float* __restrict__ gns, const float* __restrict__ gnb,
    const float* __restrict__ qkvw, const float* __restrict__ qkvb,
    bf16_t* __restrict__ qb, bf16_t* __restrict__ kb, bf16_t* __restrict__ vT) {
  __shared__ float hn[64][32];               // [c][p]
  int bx = blockIdx.x; int b = bx >> 7; int t0 = (bx & 127) << 5;
  int tid = threadIdx.x;
  {
    int c = tid >> 2, p0 = (tid & 3) << 3;
    float mu = mean[(b << 5) + (c >> 1)], rs = rstd[(b << 5) + (c >> 1)];
    float sc = gns[c] * rs, bi = gnb[c] - mu * sc;
    const float* xp = x + ((size_t)(b * 64 + c)) * NN + t0 + p0;
    #pragma unroll
    for (int j = 0; j < 8; j += 4) {
      float4 v = *reinterpret_cast<const float4*>(xp + j);
      hn[c][p0+j] = v.x*sc+bi; hn[c][p0+j+1] = v.y*sc+bi;
      hn[c][p0+j+2] = v.z*sc+bi; hn[c][p0+j+3] = v.w*sc+bi;
    }
  }
  __syncthreads();
  // q and k sections
  {
    int o0 = tid & 63, ps = tid >> 6;
    int pq = fragpos(o0);
    for (int sec = 0; sec < 2; ++sec) {
      int o = sec * 64 + o0;
      const float* wr = qkvw + o * 64;
      float acc[8];
      float bias = qkvb[o];
      #pragma unroll
      for (int m = 0; m < 8; m++) acc[m] = bias;
      for (int cc = 0; cc < 64; ++cc) {
        float wv = wr[cc];
        #pragma unroll
        for (int m = 0; m < 8; m++) acc[m] += hn[cc][ps + 4*m] * wv;
      }
      bf16_t* dst = (sec == 0) ? qb : kb;
      float mul = (sec == 0) ? SCALEV : 1.0f;
      #pragma unroll
      for (int m = 0; m < 8; m++) {
        int p = ps + 4*m;
        dst[((size_t)(b * NN) + t0 + p) * 64 + pq] = (bf16_t)(acc[m] * mul);
      }
    }
  }
  // v section
  {
    int p = tid & 31, ob = tid >> 5;
    int kk = t0 + p;
    size_t vpos = (kk & ~63) | vperm(kk & 63);
    for (int m = 0; m < 8; m++) {
      int o = 128 + ob + 8*m;
      const float* wr = qkvw + o * 64;
      float acc = qkvb[o];
      for (int cc = 0; cc < 64; ++cc) acc += hn[cc][p] * wr[cc];
      vT[((size_t)(b * 64) + (o - 128)) * NN + vpos] = (bf16_t)acc;
    }
  }
}

// ---------------- K3: flash self-attention, 32 q-rows/wave, KV-split x8 ----------------
__global__ __launch_bounds__(256, 4) void k_attn(const bf16_t* __restrict__ qb,
    const bf16_t* __restrict__ kb, const bf16_t* __restrict__ vT,
    float* __restrict__ opart, float* __restrict__ mpart, float* __restrict__ lpart) {
  int bx = blockIdx.x;
  int xcd = bx & 7;
  int b = xcd >> 1;                            // batch -> XCD pair
  int inner = ((bx >> 3) << 1) | (xcd & 1);    // 0..255
  int split = inner >> 5;                      // 0..7
  int qblk = inner & 31;                       // 0..31
  int tid = threadIdx.x; int w = tid >> 6, l = tid & 63;
  int lo = l & 15, g = l >> 4;
  int qbase = (qblk << 7) + (w << 5);          // 32 rows per wave
  const bf16_t* qrowA = qb + (((size_t)(b * NN) + qbase + lo) << 6) + g * 16;
  const bf16_t* qrowB = qrowA + (16 << 6);
  bf16x8 qfA0 = *reinterpret_cast<const bf16x8*>(qrowA);
  bf16x8 qfA1 = *reinterpret_cast<const bf16x8*>(qrowA + 8);
  bf16x8 qfB0 = *reinterpret_cast<const bf16x8*>(qrowB);
  bf16x8 qfB1 = *reinterpret_cast<const bf16x8*>(qrowB + 8);
  f32x4 oaccA[4], oaccB[4];
  #pragma unroll
  for (int nt = 0; nt < 4; nt++) {
    oaccA[nt] = (f32x4){0.f, 0.f, 0.f, 0.f};
    oaccB[nt] = (f32x4){0.f, 0.f, 0.f, 0.f};
  }
  float mA = -1e30f, lA = 0.f, mB = -1e30f, lB = 0.f;
  const bf16_t* kbB = kb + ((size_t)b * NN << 6);
  const bf16_t* vB  = vT + ((size_t)b * 64) * NN;
  int k0 = split << 9;

  #pragma unroll 1
  for (int t = 0; t < 8; ++t, k0 += 64) {
    // QK^T for both q-fragments (K loads shared)
    f32x4 sA[4], sB[4];
    #pragma unroll
    for (int c = 0; c < 4; c++) {
      const bf16_t* krow = kbB + (((size_t)(k0 + (c << 4) + lo)) << 6) + g * 16;
      bf16x8 kf0 = *reinterpret_cast<const bf16x8*>(krow);
      bf16x8 kf1 = *reinterpret_cast<const bf16x8*>(krow + 8);
      sA[c] = __builtin_amdgcn_mfma_f32_16x16x32_bf16(kf0, qfA0,
                  (f32x4){0.f, 0.f, 0.f, 0.f}, 0, 0, 0);
      sA[c] = __builtin_amdgcn_mfma_f32_16x16x32_bf16(kf1, qfA1, sA[c], 0, 0, 0);
      sB[c] = __builtin_amdgcn_mfma_f32_16x16x32_bf16(kf0, qfB0,
                  (f32x4){0.f, 0.f, 0.f, 0.f}, 0, 0, 0);
      sB[c] = __builtin_amdgcn_mfma_f32_16x16x32_bf16(kf1, qfB1, sB[c], 0, 0, 0);
    }
    // online softmax, fragment A and B
    float pmaxA = -1e30f, pmaxB = -1e30f;
    #pragma unroll
    for (int c = 0; c < 4; c++)
      #pragma unroll
      for (int r = 0; r < 4; r++) {
        pmaxA = fmaxf(pmaxA, sA[c][r]);
        pmaxB = fmaxf(pmaxB, sB[c][r]);
      }
    pmaxA = fmaxf(pmaxA, __shfl_xor(pmaxA, 16));
    pmaxA = fmaxf(pmaxA, __shfl_xor(pmaxA, 32));
    pmaxB = fmaxf(pmaxB, __shfl_xor(pmaxB, 16));
    pmaxB = fmaxf(pmaxB, __shfl_xor(pmaxB, 32));
    float mnA = fmaxf(mA, pmaxA), mnB = fmaxf(mB, pmaxB);
    float corrA = EXP2((mA - mnA) * LOG2E);
    float corrB = EXP2((mB - mnB) * LOG2E);
    // issue V(f=0) loads; softmax VALU hides latency
    bf16x8 vf[4];
    #pragma unroll
    for (int nt = 0; nt < 4; nt++)
      vf[nt] = *reinterpret_cast<const bf16x8*>(vB + ((size_t)(lo + (nt << 4))) * NN + k0 + g * 8);
    float lsA = 0.f, lsB = 0.f;
    #pragma unroll
    for (int c = 0; c < 4; c++)
      #pragma unroll
      for (int r = 0; r < 4; r++) {
        float pa = EXP2((sA[c][r] - mnA) * LOG2E);
        float pb = EXP2((sB[c][r] - mnB) * LOG2E);
        sA[c][r] = pa; sB[c][r] = pb;
        lsA += pa; lsB += pb;
      }
    lsA += __shfl_xor(lsA, 16); lsA += __shfl_xor(lsA, 32);
    lsB += __shfl_xor(lsB, 16); lsB += __shfl_xor(lsB, 32);
    lA = lA * corrA + lsA; mA = mnA;
    lB = lB * corrB + lsB; mB = mnB;
    float frA[4], frB[4];
    #pragma unroll
    for (int r = 0; r < 4; r++) {
      frA[r] = __shfl(corrA, (g << 2) + r);
      frB[r] = __shfl(corrB, (g << 2) + r);
    }
    #pragma unroll
    for (int nt = 0; nt < 4; nt++)
      #pragma unroll
      for (int r = 0; r < 4; r++) {
        oaccA[nt][r] *= frA[r];
        oaccB[nt][r] *= frB[r];
      }
    // P -> bf16 A fragments
    bf16x8 paA0, paA1, paB0, paB1;
    #pragma unroll
    for (int i = 0; i < 8; i++) {
      paA0[i] = (bf16_t)sA[i >> 2][i & 3]; paA1[i] = (bf16_t)sA[2 + (i >> 2)][i & 3];
      paB0[i] = (bf16_t)sB[i >> 2][i & 3]; paB1[i] = (bf16_t)sB[2 + (i >> 2)][i & 3];
    }
    // PV f=0
    #pragma unroll
    for (int nt = 0; nt < 4; ++nt) {
      oaccA[nt] = __builtin_amdgcn_mfma_f32_16x16x32_bf16(paA0, vf[nt], oaccA[nt], 0, 0, 0);
      oaccB[nt] = __builtin_amdgcn_mfma_f32_16x16x32_bf16(paB0, vf[nt], oaccB[nt], 0, 0, 0);
    }
    // V(f=1) loads + PV f=1
    #pragma unroll
    for (int nt = 0; nt < 4; nt++)
      vf[nt] = *reinterpret_cast<const bf16x8*>(vB + ((size_t)(lo + (nt << 4))) * NN + k0 + 32 + g * 8);
    #pragma unroll
    for (int nt = 0; nt < 4; ++nt) {
      oaccA[nt] = __builtin_amdgcn_mfma_f32_16x16x32_bf16(paA1, vf[nt], oaccA[nt], 0, 0, 0);
      oaccB[nt] = __builtin_amdgcn_mfma_f32_16x16x32_bf16(paB1, vf[nt], oaccB[nt], 0, 0, 0);
    }
  }

  size_t ob = ((size_t)(split * BN + b)) * NN + qbase;
  float liA[4], liB[4];
  #pragma unroll
  for (int r = 0; r < 4; r++) {
    liA[r] = 1.0f; liB[r] = 1.0f;   // partial outputs stay unnormalized-by-l (combine divides)
  }
  #pragma unroll
  for (int nt = 0; nt < 4; nt++)
    #pragma unroll
    for (int r = 0; r < 4; r++) {
      opart[((ob + (g << 2) + r) << 6) + lo + (nt << 4)] = oaccA[nt][r];
      opart[((ob + 16 + (g << 2) + r) << 6) + lo + (nt << 4)] = oaccB[nt][r];
    }
  if (l < 16) { mpart[ob + l] = mA; lpart[ob + l] = lA; }
  else if (l < 32) { mpart[ob + 16 + lo] = mB; lpart[ob + 16 + lo] = lB; }
}

// ---------------- K4: combine splits + proj + residual ; LayerNorm ; tq ----------------
__global__ __launch_bounds__(256) void k_proj_ln_tq(const float* __restrict__ x,
    const float* __restrict__ opart, const float* __restrict__ mpart, const float* __restrict__ lpart,
    const float* __restrict__ projw, const float* __restrict__ projb,
    const float* __restrict__ lns, const float* __restrict__ lnb,
    const float* __restrict__ wq, const float* __restrict__ bq,
    float* __restrict__ h2, float* __restrict__ tq) {
  __shared__ float sob[64][65];
  __shared__ float h2l[64][65];
  __shared__ float mu_s[64], rs_s[64];
  int bx = blockIdx.x; int b = bx >> 6; int t0 = (bx & 63) << 6;
  int tid = threadIdx.x;
  {
    int p = tid >> 2, c0 = (tid & 3) << 4;
    int q = t0 + p;
    float ms[NSPLIT], ws[NSPLIT];
    float mstar = -1e30f;
    #pragma unroll
    for (int s = 0; s < NSPLIT; s++) {
      ms[s] = mpart[((size_t)(s * BN + b)) * NN + q];
      mstar = fmaxf(mstar, ms[s]);
    }
    float denom = 0.f;
    #pragma unroll
    for (int s = 0; s < NSPLIT; s++) {
      float wv = EXP2((ms[s] - mstar) * LOG2E);
      ws[s] = wv;
      denom += wv * lpart[((size_t)(s * BN + b)) * NN + q];
    }
    float inv = 1.0f / denom;
    float acc[16];
    #pragma unroll
    for (int j = 0; j < 16; j++) acc[j] = 0.f;
    #pragma unroll
    for (int s = 0; s < NSPLIT; s++) {
      const float* op = opart + ((((size_t)(s * BN + b)) * NN + q) << 6) + c0;
      float wv = ws[s];
      #pragma unroll
      for (int j = 0; j < 16; j += 4) {
        float4 v = *reinterpret_cast<const float4*>(op + j);
        acc[j] += wv*v.x; acc[j+1] += wv*v.y; acc[j+2] += wv*v.z; acc[j+3] += wv*v.w;
      }
    }
    #pragma unroll
    for (int j = 0; j < 16; j++) sob[p][c0 + j] = acc[j] * inv;
  }
  __syncthreads();
  {
    int p = tid & 63, ob = tid >> 6;
    float acc[16];
    #pragma unroll
    for (int m = 0; m < 16; m++) {
      int o = ob + 4*m;
      acc[m] = projb[o] + x[((size_t)(b * 64) + o) * NN + t0 + p];
    }
    for (int cc = 0; cc < 64; ++cc) {
      float sv = sob[p][cc];
      #pragma unroll
      for (int m = 0; m < 16; m++) acc[m] += sv * projw[(ob + 4*m) * 64 + cc];
    }
    #pragma unroll
    for (int m = 0; m < 16; m++) {
      int o = ob + 4*m;
      h2[((size_t)(b * 64) + o) * NN + t0 + p] = acc[m];
      h2l[o][p] = acc[m];
    }
  }
  __syncthreads();
  if (tid < 64) {
    int p = tid;
    float s = 0.f, sq = 0.f;
    for (int o = 0; o < 64; o++) { float v = h2l[o][p]; s += v; sq += v*v; }
    float mu = s * (1.f/64.f);
    float var = sq * (1.f/64.f) - mu*mu;
    mu_s[p] = mu; rs_s[p] = rsqrtf(var + EPSV);
  }
  __syncthreads();
  {
    int p = tid & 63, cb = tid >> 6;
    float mu = mu_s[p], rs = rs_s[p];
    #pragma unroll
    for (int m = 0; m < 16; m++) {
      int c = cb + 4*m;
      sob[p][c] = (h2l[c][p] - mu) * rs * lns[c] + lnb[c];
    }
  }
  __syncthreads();
  {
    int o = tid & 63, pb = tid >> 6;
    float acc[16];
    #pragma unroll
    for (int m = 0; m < 16; m++) acc[m] = bq[o];
    for (int cc = 0; cc < 64; ++cc) {
      float wv = wq[cc * 64 + o];
      #pragma unroll
      for (int m = 0; m < 16; m++) acc[m] += sob[pb + 4*m][cc] * wv;
    }
    #pragma unroll
    for (int m = 0; m < 16; m++) {
      int p = pb + 4*m;
      tq[((size_t)(b * NN) + t0 + p) * 64 + o] = acc[m] * SCALEV;
    }
  }
}

// ---------------- K5: tk, tv = context @ wk/wv + b ----------------
__global__ __launch_bounds__(128) void k_tkv(const float* __restrict__ ctx,
    const float* __restrict__ wk, const float* __restrict__ bk,
    const float* __restrict__ wv, const float* __restrict__ bv,
    float* __restrict__ tk, float* __restrict__ tv) {
  __shared__ float cr[768];
  int bt = blockIdx.x;
  int tid = threadIdx.x;
  const float* src = ctx + (size_t)bt * 768;
  for (int i = tid; i < 768; i += 128) cr[i] = src[i];
  __syncthreads();
  int o = tid & 63;
  const float* w  = (tid < 64) ? wk : wv;
  const float* bb = (tid < 64) ? bk : bv;
  float acc = bb[o];
  for (int d = 0; d < 768; d++) acc += cr[d] * w[d * 64 + o];
  float* dst = (tid < 64) ? tk : tv;
  dst[(size_t)bt * 64 + o] = acc;
}

// ---------------- K6: cross-attn + scramble + final linear + residual ----------------
__global__ __launch_bounds__(256) void k_cross(const float* __restrict__ tq,
    const float* __restrict__ tkp, const float* __restrict__ tvp,
    const float* __restrict__ h2, const float* __restrict__ wo, const float* __restrict__ bo,
    float* __restrict__ out) {
  __shared__ float tqt[64][65];
  __shared__ float sP[64][80];
  __shared__ float tt[64][65];
  __shared__ float linv_s[64];
  int bx = blockIdx.x; int b = bx >> 6; int c = bx & 63;
  int tid = threadIdx.x;
  {
    int r = tid >> 2, o0 = (tid & 3) << 4;
    const float* src = tq + ((size_t)(b * NN) + (c << 6) + r) * 64 + o0;
    #pragma unroll
    for (int j = 0; j < 16; j += 4) {
      float4 v = *reinterpret_cast<const float4*>(src + j);
      tqt[r][o0+j] = v.x; tqt[r][o0+j+1] = v.y; tqt[r][o0+j+2] = v.z; tqt[r][o0+j+3] = v.w;
    }
  }
  __syncthreads();
  {
    int r = tid >> 2, q = tid & 3;
    const float* tkb = tkp + (size_t)b * TN * 64;
    for (int tok = q; tok < TN; tok += 4) {
      const float* krow = tkb + tok * 64;
      float acc = 0.f;
      for (int o = 0; o < 64; o++) acc += tqt[r][o] * krow[o];
      sP[r][tok] = acc;
    }
    float mx = -1e30f;
    for (int tok = q; tok < TN; tok += 4) mx = fmaxf(mx, sP[r][tok]);
    mx = fmaxf(mx, __shfl_xor(mx, 1));
    mx = fmaxf(mx, __shfl_xor(mx, 2));
    float ls = 0.f;
    for (int tok = q; tok < TN; tok += 4) {
      float pv = EXP2((sP[r][tok] - mx) * LOG2E);
      sP[r][tok] = pv; ls += pv;
    }
    ls += __shfl_xor(ls, 1);
    ls += __shfl_xor(ls, 2);
    if (q == 0) linv_s[r] = 1.0f / ls;
  }
  __syncthreads();
  {
    int o = tid & 63, rb = tid >> 6;
    const float* tvb = tvp + (size_t)b * TN * 64;
    float acc[16];
    #pragma unroll
    for (int m = 0; m < 16; m++) acc[m] = 0.f;
    for (int tok = 0; tok < TN; tok++) {
      float vv = tvb[tok * 64 + o];
      #pragma unroll
      for (int m = 0; m < 16; m++) acc[m] += sP[rb + 4*m][tok] * vv;
    }
    #pragma unroll
    for (int m = 0; m < 16; m++) {
      int r = rb + 4*m;
      tt[r][o] = acc[m] * linv_s[r];
    }
  }
  __syncthreads();
  {
    int ww = tid & 63, hb = tid >> 6;
    const float* h2r = h2 + ((size_t)(b * 64) + c) * NN;
    float bov = bo[ww];
    float acc[16];
    #pragma unroll
    for (int m = 0; m < 16; m++) acc[m] = h2r[((hb + 4*m) << 6) + ww] + bov;
    for (int k = 0; k < 64; k++) {
      float wv = wo[(k << 6) + ww];
      #pragma unroll
      for (int m = 0; m < 16; m++) acc[m] += tt[k][hb + 4*m] * wv;
    }
    #pragma unroll
    for (int m = 0; m < 16; m++)
      out[((size_t)(b * 64) + c) * NN + ((hb + 4*m) << 6) + ww] = acc[m];
  }
}

extern "C" void kernel_launch(void* const* d_in, const int* in_sizes, int n_in,
                              void* d_out, int out_size, void* d_ws, size_t ws_size,
                              hipStream_t stream) {
  const float* x     = (const float*)d_in[0];
  const float* ctx   = (const float*)d_in[1];
  const float* gns   = (const float*)d_in[2];
  const float* gnb   = (const float*)d_in[3];
  const float* qkvw  = (const float*)d_in[4];
  const float* qkvb  = (const float*)d_in[5];
  const float* projw = (const float*)d_in[6];
  const float* projb = (const float*)d_in[7];
  const float* lns   = (const float*)d_in[8];
  const float* lnb   = (const float*)d_in[9];
  const float* wq    = (const float*)d_in[10];
  const float* bq    = (const float*)d_in[11];
  const float* wk    = (const float*)d_in[12];
  const float* bk    = (const float*)d_in[13];
  const float* wv    = (const float*)d_in[14];
  const float* bv    = (const float*)d_in[15];
  const float* wo    = (const float*)d_in[16];
  const float* bo    = (const float*)d_in[17];
  float* out = (float*)d_out;

  char* ws = (char*)d_ws;
  float* gmean = (float*)ws;                       // 128
  float* grstd = gmean + 128;                      // 128
  bf16_t* qb   = (bf16_t*)(ws + 1024);
  bf16_t* kbuf = qb + (size_t)BN * NN * 64;
  bf16_t* vT   = kbuf + (size_t)BN * NN * 64;
  float* opart = (float*)(ws + 1024 + 3 * (size_t)BN * NN * 64 * 2);  // 32 MB
  float* mpart = opart + (size_t)NSPLIT * BN * NN * 64;
  float* lpart = mpart + (size_t)NSPLIT * BN * NN;
  float* h2  = lpart + (size_t)NSPLIT * BN * NN;
  float* tqb = h2 + (size_t)BN * NN * 64;
  float* tkb = tqb + (size_t)BN * NN * 64;
  float* tvb = tkb + (size_t)BN * TN * 64;

  k_gnstats<<<dim3(128), dim3(256), 0, stream>>>(x, gmean, grstd);
  k_gn_qkv<<<dim3(512), dim3(256), 0, stream>>>(x, gmean, grstd, gns, gnb, qkvw, qkvb,
                                                qb, kbuf, vT);
  k_attn<<<dim3(1024), dim3(256), 0, stream>>>(qb, kbuf, vT, opart, mpart, lpart);
  k_proj_ln_tq<<<dim3(256), dim3(256), 0, stream>>>(x, opart, mpart, lpart, projw, projb,
                                                    lns, lnb, wq, bq, h2, tqb);
  k_tkv<<<dim3(BN * TN), dim3(128), 0, stream>>>(ctx, wk, bk, wv, bv, tkb, tvb);
  k_cross<<<dim3(256), dim3(256), 0, stream>>>(tqb, tkb, tvb, h2, wo, bo, out);
}

// Round 4
// 158.401 us; speedup vs baseline: 2.8445x; 1.3961x over previous
//
#include <hip/hip_runtime.h>
#include <cstdint>
#include <cstddef>

#define BN 4
#define CN 64
#define NN 4096
#define GN 32
#define TN 77
#define DN 768
#define EPSV 1e-5f
#define SCALEV 0.125f
#define LOG2E 1.4426950408889634f
#define NSPLIT 8

typedef __bf16 bf16_t;
typedef __attribute__((ext_vector_type(8))) __bf16 bf16x8;
typedef __attribute__((ext_vector_type(4))) __bf16 bf16x4;
typedef __attribute__((ext_vector_type(4))) float f32x4;

#define EXP2(x) __builtin_amdgcn_exp2f(x)

// ---------------- K1: GroupNorm partial stats (256 blocks: (b,g,half)) ----------------
__global__ __launch_bounds__(256) void k_gnstats(const float* __restrict__ x,
                                                 float* __restrict__ gpart) {
  int bx = blockIdx.x;                      // bg = bx>>1, half = bx&1; base = bx*4096
  const float4* base = reinterpret_cast<const float4*>(x + (size_t)bx * 4096);
  float s = 0.f, sq = 0.f;
  for (int i = threadIdx.x; i < 1024; i += 256) {
    float4 v = base[i];
    s  += v.x + v.y + v.z + v.w;
    sq += v.x*v.x + v.y*v.y + v.z*v.z + v.w*v.w;
  }
  for (int off = 32; off; off >>= 1) { s += __shfl_down(s, off); sq += __shfl_down(sq, off); }
  __shared__ float ss[4], ssq[4];
  int w = threadIdx.x >> 6, l = threadIdx.x & 63;
  if (l == 0) { ss[w] = s; ssq[w] = sq; }
  __syncthreads();
  if (threadIdx.x == 0) {
    // layout: gpart[bg*4 + half*2 + {0,1}] = {s, sq}
    gpart[bx * 2]     = ss[0] + ss[1] + ss[2] + ss[3];
    gpart[bx * 2 + 1] = ssq[0] + ssq[1] + ssq[2] + ssq[3];
  }
}

// fragment-order channel permutation for Q/K rows (slot position of channel o)
__device__ __forceinline__ int fragpos(int o) {
  return ((o >> 2) & 3) * 16 + ((o >> 4) & 1) * 4 + ((o >> 5) & 1) * 8 + (o & 3);
}
// within-64-key permutation for V rows
__device__ __forceinline__ int vperm(int p) {
  return (p & 32) + ((p >> 2) & 3) * 8 + ((p >> 4) & 1) * 4 + (p & 3);
}

// ---------------- K2: GN apply + QKV 1x1; 32-position tiles (512 blocks) ----------------
__global__ __launch_bounds__(256) void k_gn_qkv(const float* __restrict__ x,
    const float* __restrict__ gpart,
    const float* __restrict__ gns, const float* __restrict__ gnb,
    const float* __restrict__ qkvw, const float* __restrict__ qkvb,
    bf16_t* __restrict__ qb, bf16_t* __restrict__ kb, bf16_t* __restrict__ vT) {
  __shared__ float hn[64][32];               // [c][p]
  int bx = blockIdx.x; int b = bx >> 7; int t0 = (bx & 127) << 5;
  int tid = threadIdx.x;
  {
    int c = tid >> 2, p0 = (tid & 3) << 3;
    float4 gp = *reinterpret_cast<const float4*>(gpart + (((b << 5) + (c >> 1)) << 2));
    float mu = (gp.x + gp.z) * (1.f / 8192.f);
    float e2 = (gp.y + gp.w) * (1.f / 8192.f);
    float rs = rsqrtf(e2 - mu * mu + EPSV);
    float sc = gns[c] * rs, bi = gnb[c] - mu * sc;
    const float* xp = x + ((size_t)(b * 64 + c)) * NN + t0 + p0;
    #pragma unroll
    for (int j = 0; j < 8; j += 4) {
      float4 v = *reinterpret_cast<const float4*>(xp + j);
      hn[c][p0+j] = v.x*sc+bi; hn[c][p0+j+1] = v.y*sc+bi;
      hn[c][p0+j+2] = v.z*sc+bi; hn[c][p0+j+3] = v.w*sc+bi;
    }
  }
  __syncthreads();
  // q and k sections
  {
    int o0 = tid & 63, ps = tid >> 6;
    int pq = fragpos(o0);
    for (int sec = 0; sec < 2; ++sec) {
      int o = sec * 64 + o0;
      const float* wr = qkvw + o * 64;
      float acc[8];
      float bias = qkvb[o];
      #pragma unroll
      for (int m = 0; m < 8; m++) acc[m] = bias;
      for (int cc = 0; cc < 64; ++cc) {
        float wv = wr[cc];
        #pragma unroll
        for (int m = 0; m < 8; m++) acc[m] += hn[cc][ps + 4*m] * wv;
      }
      bf16_t* dst = (sec == 0) ? qb : kb;
      float mul = (sec == 0) ? (SCALEV * LOG2E) : 1.0f;   // q carries softmax log2 scale
      #pragma unroll
      for (int m = 0; m < 8; m++) {
        int p = ps + 4*m;
        dst[((size_t)(b * NN) + t0 + p) * 64 + pq] = (bf16_t)(acc[m] * mul);
      }
    }
  }
  // v section
  {
    int p = tid & 31, ob = tid >> 5;
    int kk = t0 + p;
    size_t vpos = (kk & ~63) | vperm(kk & 63);
    for (int m = 0; m < 8; m++) {
      int o = 128 + ob + 8*m;
      const float* wr = qkvw + o * 64;
      float acc = qkvb[o];
      for (int cc = 0; cc < 64; ++cc) acc += hn[cc][p] * wr[cc];
      vT[((size_t)(b * 64) + (o - 128)) * NN + vpos] = (bf16_t)acc;
    }
  }
}

// ---------------- K3: flash self-attention, 32 q-rows/wave, KV-split x8 ----------------
// Partials stored normalized (O/l) in bf16; m,l in fp32 (log2 domain).
__global__ __launch_bounds__(256, 4) void k_attn(const bf16_t* __restrict__ qb,
    const bf16_t* __restrict__ kb, const bf16_t* __restrict__ vT,
    bf16_t* __restrict__ opart, float* __restrict__ mpart, float* __restrict__ lpart) {
  int bx = blockIdx.x;
  int xcd = bx & 7;
  int b = xcd >> 1;                            // batch -> XCD pair
  int inner = ((bx >> 3) << 1) | (xcd & 1);    // 0..255
  int split = inner >> 5;                      // 0..7
  int qblk = inner & 31;                       // 0..31
  int tid = threadIdx.x; int w = tid >> 6, l = tid & 63;
  int lo = l & 15, g = l >> 4;
  int qbase = (qblk << 7) + (w << 5);          // 32 rows per wave
  const bf16_t* qrowA = qb + (((size_t)(b * NN) + qbase + lo) << 6) + g * 16;
  const bf16_t* qrowB = qrowA + (16 << 6);
  bf16x8 qfA0 = *reinterpret_cast<const bf16x8*>(qrowA);
  bf16x8 qfA1 = *reinterpret_cast<const bf16x8*>(qrowA + 8);
  bf16x8 qfB0 = *reinterpret_cast<const bf16x8*>(qrowB);
  bf16x8 qfB1 = *reinterpret_cast<const bf16x8*>(qrowB + 8);
  f32x4 oaccA[4], oaccB[4];
  #pragma unroll
  for (int nt = 0; nt < 4; nt++) {
    oaccA[nt] = (f32x4){0.f, 0.f, 0.f, 0.f};
    oaccB[nt] = (f32x4){0.f, 0.f, 0.f, 0.f};
  }
  float mA = -1e30f, lA = 0.f, mB = -1e30f, lB = 0.f;
  const bf16_t* kbB = kb + ((size_t)b * NN << 6);
  const bf16_t* vB  = vT + ((size_t)b * 64) * NN;
  int k0 = split << 9;

  #pragma unroll 1
  for (int t = 0; t < 8; ++t, k0 += 64) {
    // QK^T for both q-fragments (K loads shared); scores already in log2 units
    f32x4 sA[4], sB[4];
    #pragma unroll
    for (int c = 0; c < 4; c++) {
      const bf16_t* krow = kbB + (((size_t)(k0 + (c << 4) + lo)) << 6) + g * 16;
      bf16x8 kf0 = *reinterpret_cast<const bf16x8*>(krow);
      bf16x8 kf1 = *reinterpret_cast<const bf16x8*>(krow + 8);
      sA[c] = __builtin_amdgcn_mfma_f32_16x16x32_bf16(kf0, qfA0,
                  (f32x4){0.f, 0.f, 0.f, 0.f}, 0, 0, 0);
      sA[c] = __builtin_amdgcn_mfma_f32_16x16x32_bf16(kf1, qfA1, sA[c], 0, 0, 0);
      sB[c] = __builtin_amdgcn_mfma_f32_16x16x32_bf16(kf0, qfB0,
                  (f32x4){0.f, 0.f, 0.f, 0.f}, 0, 0, 0);
      sB[c] = __builtin_amdgcn_mfma_f32_16x16x32_bf16(kf1, qfB1, sB[c], 0, 0, 0);
    }
    // lane-local maxima (all 16 values belong to q-row lo)
    float pmaxA = -1e30f, pmaxB = -1e30f;
    #pragma unroll
    for (int c = 0; c < 4; c++)
      #pragma unroll
      for (int r = 0; r < 4; r++) {
        pmaxA = fmaxf(pmaxA, sA[c][r]);
        pmaxB = fmaxf(pmaxB, sB[c][r]);
      }
    // defer-rescale: only reduce+rescale when some row exceeds m+8 (log2 units)
    if (!__all(pmaxA - mA <= 8.f)) {
      pmaxA = fmaxf(pmaxA, __shfl_xor(pmaxA, 16));
      pmaxA = fmaxf(pmaxA, __shfl_xor(pmaxA, 32));
      float mn = fmaxf(mA, pmaxA);
      float corr = EXP2(mA - mn);
      lA *= corr; mA = mn;
      float fr[4];
      #pragma unroll
      for (int r = 0; r < 4; r++) fr[r] = __shfl(corr, (g << 2) + r);
      #pragma unroll
      for (int nt = 0; nt < 4; nt++)
        #pragma unroll
        for (int r = 0; r < 4; r++) oaccA[nt][r] *= fr[r];
    }
    if (!__all(pmaxB - mB <= 8.f)) {
      pmaxB = fmaxf(pmaxB, __shfl_xor(pmaxB, 16));
      pmaxB = fmaxf(pmaxB, __shfl_xor(pmaxB, 32));
      float mn = fmaxf(mB, pmaxB);
      float corr = EXP2(mB - mn);
      lB *= corr; mB = mn;
      float fr[4];
      #pragma unroll
      for (int r = 0; r < 4; r++) fr[r] = __shfl(corr, (g << 2) + r);
      #pragma unroll
      for (int nt = 0; nt < 4; nt++)
        #pragma unroll
        for (int r = 0; r < 4; r++) oaccB[nt][r] *= fr[r];
    }
    // issue V(f=0) loads; exp VALU hides latency
    bf16x8 vf[4];
    #pragma unroll
    for (int nt = 0; nt < 4; nt++)
      vf[nt] = *reinterpret_cast<const bf16x8*>(vB + ((size_t)(lo + (nt << 4))) * NN + k0 + g * 8);
    float lsA = 0.f, lsB = 0.f;
    #pragma unroll
    for (int c = 0; c < 4; c++)
      #pragma unroll
      for (int r = 0; r < 4; r++) {
        float pa = EXP2(sA[c][r] - mA);
        float pb = EXP2(sB[c][r] - mB);
        sA[c][r] = pa; sB[c][r] = pb;
        lsA += pa; lsB += pb;
      }
    lsA += __shfl_xor(lsA, 16); lsA += __shfl_xor(lsA, 32);
    lsB += __shfl_xor(lsB, 16); lsB += __shfl_xor(lsB, 32);
    lA += lsA; lB += lsB;
    // P -> bf16 A fragments
    bf16x8 paA0, paA1, paB0, paB1;
    #pragma unroll
    for (int i = 0; i < 8; i++) {
      paA0[i] = (bf16_t)sA[i >> 2][i & 3]; paA1[i] = (bf16_t)sA[2 + (i >> 2)][i & 3];
      paB0[i] = (bf16_t)sB[i >> 2][i & 3]; paB1[i] = (bf16_t)sB[2 + (i >> 2)][i & 3];
    }
    // PV f=0
    #pragma unroll
    for (int nt = 0; nt < 4; ++nt) {
      oaccA[nt] = __builtin_amdgcn_mfma_f32_16x16x32_bf16(paA0, vf[nt], oaccA[nt], 0, 0, 0);
      oaccB[nt] = __builtin_amdgcn_mfma_f32_16x16x32_bf16(paB0, vf[nt], oaccB[nt], 0, 0, 0);
    }
    // V(f=1) loads + PV f=1
    #pragma unroll
    for (int nt = 0; nt < 4; nt++)
      vf[nt] = *reinterpret_cast<const bf16x8*>(vB + ((size_t)(lo + (nt << 4))) * NN + k0 + 32 + g * 8);
    #pragma unroll
    for (int nt = 0; nt < 4; ++nt) {
      oaccA[nt] = __builtin_amdgcn_mfma_f32_16x16x32_bf16(paA1, vf[nt], oaccA[nt], 0, 0, 0);
      oaccB[nt] = __builtin_amdgcn_mfma_f32_16x16x32_bf16(paB1, vf[nt], oaccB[nt], 0, 0, 0);
    }
  }

  size_t ob = ((size_t)(split * BN + b)) * NN + qbase;
  float liA[4], liB[4];
  #pragma unroll
  for (int r = 0; r < 4; r++) {
    liA[r] = 1.0f / __shfl(lA, (g << 2) + r);
    liB[r] = 1.0f / __shfl(lB, (g << 2) + r);
  }
  #pragma unroll
  for (int nt = 0; nt < 4; nt++)
    #pragma unroll
    for (int r = 0; r < 4; r++) {
      opart[((ob + (g << 2) + r) << 6) + lo + (nt << 4)] = (bf16_t)(oaccA[nt][r] * liA[r]);
      opart[((ob + 16 + (g << 2) + r) << 6) + lo + (nt << 4)] = (bf16_t)(oaccB[nt][r] * liB[r]);
    }
  if (l < 16) { mpart[ob + l] = mA; lpart[ob + l] = lA; }
  else if (l < 32) { mpart[ob + 16 + lo] = mB; lpart[ob + 16 + lo] = lB; }
}

// ---------------- K4: combine splits + proj + residual ; LayerNorm ; tq ----------------
// 32-position tiles -> 512 blocks
__global__ __launch_bounds__(256) void k_proj_ln_tq(const float* __restrict__ x,
    const bf16_t* __restrict__ opart, const float* __restrict__ mpart, const float* __restrict__ lpart,
    const float* __restrict__ projw, const float* __restrict__ projb,
    const float* __restrict__ lns, const float* __restrict__ lnb,
    const float* __restrict__ wq, const float* __restrict__ bq,
    float* __restrict__ h2, float* __restrict__ tq) {
  __shared__ float sob[32][65];   // self_out [p][c], later reused as tf
  __shared__ float h2l[64][33];   // h2 tile [o][p]
  __shared__ float r1[8][32], r2[8][32];
  __shared__ float mu_s[32], rs_s[32];
  int bx = blockIdx.x; int b = bx >> 7; int t0 = (bx & 127) << 5;
  int tid = threadIdx.x;
  {
    int p = tid >> 3, c0 = (tid & 7) << 3;
    int q = t0 + p;
    float ms[NSPLIT];
    float mstar = -1e30f;
    #pragma unroll
    for (int s = 0; s < NSPLIT; s++) {
      ms[s] = mpart[((size_t)(s * BN + b)) * NN + q];
      mstar = fmaxf(mstar, ms[s]);
    }
    float co[NSPLIT]; float denom = 0.f;
    #pragma unroll
    for (int s = 0; s < NSPLIT; s++) {
      co[s] = EXP2(ms[s] - mstar) * lpart[((size_t)(s * BN + b)) * NN + q];
      denom += co[s];
    }
    float inv = 1.0f / denom;
    float acc[8];
    #pragma unroll
    for (int j = 0; j < 8; j++) acc[j] = 0.f;
    #pragma unroll
    for (int s = 0; s < NSPLIT; s++) {
      bf16x8 v = *reinterpret_cast<const bf16x8*>(
          opart + ((((size_t)(s * BN + b)) * NN + q) << 6) + c0);
      float wv = co[s];
      #pragma unroll
      for (int j = 0; j < 8; j++) acc[j] += wv * (float)v[j];
    }
    #pragma unroll
    for (int j = 0; j < 8; j++) sob[p][c0 + j] = acc[j] * inv;
  }
  __syncthreads();
  {
    int p = tid & 31, ob = tid >> 5;
    float acc[8];
    #pragma unroll
    for (int m = 0; m < 8; m++) {
      int o = ob + 8*m;
      acc[m] = projb[o] + x[((size_t)(b * 64) + o) * NN + t0 + p];
    }
    for (int cc = 0; cc < 64; ++cc) {
      float sv = sob[p][cc];
      #pragma unroll
      for (int m = 0; m < 8; m++) acc[m] += sv * projw[(ob + 8*m) * 64 + cc];
    }
    #pragma unroll
    for (int m = 0; m < 8; m++) {
      int o = ob + 8*m;
      h2[((size_t)(b * 64) + o) * NN + t0 + p] = acc[m];
      h2l[o][p] = acc[m];
    }
  }
  __syncthreads();
  {
    int p = tid & 31, og = tid >> 5;
    float s = 0.f, sq = 0.f;
    #pragma unroll
    for (int j = 0; j < 8; j++) { float v = h2l[og * 8 + j][p]; s += v; sq += v*v; }
    r1[og][p] = s; r2[og][p] = sq;
  }
  __syncthreads();
  if (tid < 32) {
    float s = 0.f, sq = 0.f;
    #pragma unroll
    for (int j = 0; j < 8; j++) { s += r1[j][tid]; sq += r2[j][tid]; }
    float mu = s * (1.f/64.f);
    float var = sq * (1.f/64.f) - mu*mu;
    mu_s[tid] = mu; rs_s[tid] = rsqrtf(var + EPSV);
  }
  __syncthreads();
  {
    int p = tid & 31, cb = tid >> 5;
    float mu = mu_s[p], rs = rs_s[p];
    #pragma unroll
    for (int m = 0; m < 8; m++) {
      int c = cb + 8*m;
      sob[p][c] = (h2l[c][p] - mu) * rs * lns[c] + lnb[c];
    }
  }
  __syncthreads();
  {
    int o = tid & 63, pb = tid >> 6;
    float acc[8];
    #pragma unroll
    for (int m = 0; m < 8; m++) acc[m] = bq[o];
    for (int cc = 0; cc < 64; ++cc) {
      float wv = wq[cc * 64 + o];
      #pragma unroll
      for (int m = 0; m < 8; m++) acc[m] += sob[pb + 4*m][cc] * wv;
    }
    #pragma unroll
    for (int m = 0; m < 8; m++) {
      int p = pb + 4*m;
      tq[((size_t)(b * NN) + t0 + p) * 64 + o] = acc[m] * (SCALEV * LOG2E);
    }
  }
}

// ---------------- K5: tk, tv = context @ wk/wv + b (d-split over 4 sections) ----------------
__global__ __launch_bounds__(256) void k_tkv(const float* __restrict__ ctx,
    const float* __restrict__ wk, const float* __restrict__ bk,
    const float* __restrict__ wv, const float* __restrict__ bv,
    float* __restrict__ tk, float* __restrict__ tv) {
  __shared__ float cr[768];
  __shared__ float red[4][64];
  int bt = blockIdx.x;
  int tid = threadIdx.x;
  const float* src = ctx + (size_t)bt * 768;
  for (int i = tid; i < 768; i += 256) cr[i] = src[i];
  __syncthreads();
  int o = tid & 63, sec = tid >> 6;
  int sel = sec & 1, dh = sec >> 1;
  const float* w = (sel ? wv : wk) + dh * 384 * 64;
  const float* c0 = cr + dh * 384;
  float acc = 0.f;
  for (int d = 0; d < 384; d++) acc += c0[d] * w[d * 64 + o];
  red[sec][o] = acc;
  __syncthreads();
  if (tid < 128) {
    int s2 = tid >> 6; int oo = tid & 63;
    float r = red[s2][oo] + red[s2 + 2][oo] + (s2 ? bv[oo] : bk[oo]);
    float* dst = s2 ? tv : tk;
    dst[(size_t)bt * 64 + oo] = r;
  }
}

// ---------------- K6a: cross-attn -> tout (512 blocks of 32 rows) ----------------
__global__ __launch_bounds__(256) void k_cross1(const float* __restrict__ tq,
    const float* __restrict__ tkp, const float* __restrict__ tvp,
    float* __restrict__ tout) {
  __shared__ float tqt[32][65];
  __shared__ float tkl[77][65];
  __shared__ float sP[32][80];
  __shared__ float linv_s[32];
  int bx = blockIdx.x; int b = bx >> 7; int n0 = (bx & 127) << 5;
  int tid = threadIdx.x;
  {
    int r = tid >> 3, o0 = (tid & 7) << 3;
    const float* src = tq + ((size_t)(b * NN) + n0 + r) * 64 + o0;
    float4 v1 = *reinterpret_cast<const float4*>(src);
    float4 v2 = *reinterpret_cast<const float4*>(src + 4);
    tqt[r][o0+0]=v1.x; tqt[r][o0+1]=v1.y; tqt[r][o0+2]=v1.z; tqt[r][o0+3]=v1.w;
    tqt[r][o0+4]=v2.x; tqt[r][o0+5]=v2.y; tqt[r][o0+6]=v2.z; tqt[r][o0+7]=v2.w;
  }
  {
    const float* tkb = tkp + (size_t)b * TN * 64;
    for (int i = tid; i < TN * 64; i += 256) tkl[i >> 6][i & 63] = tkb[i];
  }
  __syncthreads();
  {
    int r = tid >> 3, qq = tid & 7;
    float sv[10]; int cnt = 0;
    float mx = -1e30f;
    for (int tok = qq; tok < TN; tok += 8) {
      float acc = 0.f;
      for (int o = 0; o < 64; o++) acc += tqt[r][o] * tkl[tok][o];
      sv[cnt++] = acc; mx = fmaxf(mx, acc);
    }
    mx = fmaxf(mx, __shfl_xor(mx, 1));
    mx = fmaxf(mx, __shfl_xor(mx, 2));
    mx = fmaxf(mx, __shfl_xor(mx, 4));
    float ls = 0.f; cnt = 0;
    for (int tok = qq; tok < TN; tok += 8) {
      float pv = EXP2(sv[cnt++] - mx);   // tq carries log2 scale
      sP[r][tok] = pv; ls += pv;
    }
    ls += __shfl_xor(ls, 1);
    ls += __shfl_xor(ls, 2);
    ls += __shfl_xor(ls, 4);
    if (qq == 0) linv_s[r] = 1.0f / ls;
  }
  __syncthreads();
  {
    int o = tid & 63, rb = tid >> 6;
    const float* tvb = tvp + (size_t)b * TN * 64;
    float acc[8];
    #pragma unroll
    for (int m = 0; m < 8; m++) acc[m] = 0.f;
    for (int tok = 0; tok < TN; tok++) {
      float vv = tvb[tok * 64 + o];
      #pragma unroll
      for (int m = 0; m < 8; m++) acc[m] += sP[rb + 4*m][tok] * vv;
    }
    #pragma unroll
    for (int m = 0; m < 8; m++) {
      int r = rb + 4*m;
      tout[((size_t)(b * NN) + n0 + r) * 64 + o] = acc[m] * linv_s[r];
    }
  }
}

// ---------------- K6b: scramble + final linear + residual (512 blocks) ----------------
__global__ __launch_bounds__(256) void k_cross2(const float* __restrict__ tout,
    const float* __restrict__ h2, const float* __restrict__ wo, const float* __restrict__ bo,
    float* __restrict__ out) {
  __shared__ float tl[64][33];
  int bx = blockIdx.x; int b = bx >> 7; int c1 = (bx >> 1) & 63; int half = bx & 1;
  int tid = threadIdx.x;
  {
    int k = tid >> 2, j0 = (tid & 3) << 3;
    const float* src = tout + ((size_t)(b * NN) + c1 * 64 + k) * 64 + half * 32 + j0;
    float4 v1 = *reinterpret_cast<const float4*>(src);
    float4 v2 = *reinterpret_cast<const float4*>(src + 4);
    tl[k][j0+0]=v1.x; tl[k][j0+1]=v1.y; tl[k][j0+2]=v1.z; tl[k][j0+3]=v1.w;
    tl[k][j0+4]=v2.x; tl[k][j0+5]=v2.y; tl[k][j0+6]=v2.z; tl[k][j0+7]=v2.w;
  }
  __syncthreads();
  int w = tid & 63, c2b = tid >> 6;
  float bov = bo[w];
  float acc[8];
  #pragma unroll
  for (int m = 0; m < 8; m++) {
    int c2 = half * 32 + c2b + 4*m;
    acc[m] = h2[((size_t)(b * 64) + c1) * NN + c2 * 64 + w] + bov;
  }
  for (int k = 0; k < 64; k++) {
    float wv = wo[k * 64 + w];
    #pragma unroll
    for (int m = 0; m < 8; m++) acc[m] += tl[k][c2b + 4*m] * wv;
  }
  #pragma unroll
  for (int m = 0; m < 8; m++) {
    int c2 = half * 32 + c2b + 4*m;
    out[((size_t)(b * 64) + c1) * NN + c2 * 64 + w] = acc[m];
  }
}

extern "C" void kernel_launch(void* const* d_in, const int* in_sizes, int n_in,
                              void* d_out, int out_size, void* d_ws, size_t ws_size,
                              hipStream_t stream) {
  const float* x     = (const float*)d_in[0];
  const float* ctx   = (const float*)d_in[1];
  const float* gns   = (const float*)d_in[2];
  const float* gnb   = (const float*)d_in[3];
  const float* qkvw  = (const float*)d_in[4];
  const float* qkvb  = (const float*)d_in[5];
  const float* projw = (const float*)d_in[6];
  const float* projb = (const float*)d_in[7];
  const float* lns   = (const float*)d_in[8];
  const float* lnb   = (const float*)d_in[9];
  const float* wq    = (const float*)d_in[10];
  const float* bq    = (const float*)d_in[11];
  const float* wk    = (const float*)d_in[12];
  const float* bk    = (const float*)d_in[13];
  const float* wv    = (const float*)d_in[14];
  const float* bv    = (const float*)d_in[15];
  const float* wo    = (const float*)d_in[16];
  const float* bo    = (const float*)d_in[17];
  float* out = (float*)d_out;

  char* ws = (char*)d_ws;
  float* gpart = (float*)ws;                       // 512 floats
  bf16_t* qb   = (bf16_t*)(ws + 4096);
  bf16_t* kbuf = qb + (size_t)BN * NN * 64;
  bf16_t* vT   = kbuf + (size_t)BN * NN * 64;
  bf16_t* opart = vT + (size_t)BN * NN * 64;                       // 16 MB bf16
  float* mpart = (float*)(opart + (size_t)NSPLIT * BN * NN * 64);
  float* lpart = mpart + (size_t)NSPLIT * BN * NN;
  float* h2    = lpart + (size_t)NSPLIT * BN * NN;
  float* tqb   = h2 + (size_t)BN * NN * 64;
  float* toutb = tqb + (size_t)BN * NN * 64;
  float* tkb   = toutb + (size_t)BN * NN * 64;
  float* tvb   = tkb + (size_t)BN * TN * 64;

  k_gnstats<<<dim3(256), dim3(256), 0, stream>>>(x, gpart);
  k_gn_qkv<<<dim3(512), dim3(256), 0, stream>>>(x, gpart, gns, gnb, qkvw, qkvb,
                                                qb, kbuf, vT);
  k_attn<<<dim3(1024), dim3(256), 0, stream>>>(qb, kbuf, vT, opart, mpart, lpart);
  k_proj_ln_tq<<<dim3(512), dim3(256), 0, stream>>>(x, opart, mpart, lpart, projw, projb,
                                                    lns, lnb, wq, bq, h2, tqb);
  k_tkv<<<dim3(BN * TN), dim3(256), 0, stream>>>(ctx, wk, bk, wv, bv, tkb, tvb);
  k_cross1<<<dim3(512), dim3(256), 0, stream>>>(tqb, tkb, tvb, toutb);
  k_cross2<<<dim3(512), dim3(256), 0, stream>>>(toutb, h2, wo, bo, out);
}